// Round 7
// baseline (1330.460 us; speedup 1.0000x reference)
//
#include <hip/hip_runtime.h>
#include <stdint.h>

typedef __bf16 bf16x8 __attribute__((ext_vector_type(8)));
typedef _Float16 f16x8 __attribute__((ext_vector_type(8)));
typedef float f32x4 __attribute__((ext_vector_type(4)));

#define BETA 0.25f

__device__ __forceinline__ unsigned short f2bf(float f) {
    __bf16 h = (__bf16)f;
    return __builtin_bit_cast(unsigned short, h);
}

__device__ __forceinline__ unsigned short f2h(float f) {
    _Float16 h = (_Float16)f;
    return __builtin_bit_cast(unsigned short, h);
}

// Split 8 f32 -> f16 hi + f16 lo*2^11, packed as uint4 each.
__device__ __forceinline__ void split8(const float* a, uint4& vh, uint4& vl) {
    unsigned h[8], l[8];
#pragma unroll
    for (int j = 0; j < 8; ++j) {
        _Float16 hi = (_Float16)a[j];
        float hf = (float)hi;
        _Float16 lo = (_Float16)((a[j] - hf) * 2048.0f);
        h[j] = (unsigned)__builtin_bit_cast(unsigned short, hi);
        l[j] = (unsigned)__builtin_bit_cast(unsigned short, lo);
    }
    vh.x = h[0] | (h[1] << 16); vh.y = h[2] | (h[3] << 16);
    vh.z = h[4] | (h[5] << 16); vh.w = h[6] | (h[7] << 16);
    vl.x = l[0] | (l[1] << 16); vl.y = l[2] | (l[3] << 16);
    vl.z = l[4] | (l[5] << 16); vl.w = l[6] | (l[7] << 16);
}

// ---------------------------------------------------------------------------
// Weight split + transpose: W[K,N] f32 -> WTh,WTl [N,K] f16 (x32 scaled).
// ---------------------------------------------------------------------------
__global__ __launch_bounds__(256) void wsplit_t(
    const float* __restrict__ W, unsigned short* __restrict__ WTh,
    unsigned short* __restrict__ WTl, int K, int N)
{
    __shared__ float tile[32][33];
    const int t = threadIdx.x;
    const int n0 = blockIdx.x * 32, k0 = blockIdx.y * 32;
    const int rr = t >> 3, c4 = (t & 7) * 4;
    float4 w = *(const float4*)(W + (size_t)(k0 + rr) * N + n0 + c4);
    tile[rr][c4 + 0] = w.x; tile[rr][c4 + 1] = w.y;
    tile[rr][c4 + 2] = w.z; tile[rr][c4 + 3] = w.w;
    __syncthreads();
    float v[4] = {tile[c4 + 0][rr], tile[c4 + 1][rr],
                  tile[c4 + 2][rr], tile[c4 + 3][rr]};
    unsigned short hh[4], ll[4];
#pragma unroll
    for (int j = 0; j < 4; ++j) {
        float s = v[j] * 32.0f;
        _Float16 hi = (_Float16)s;
        float hf = (float)hi;
        hh[j] = __builtin_bit_cast(unsigned short, hi);
        ll[j] = f2h((s - hf) * 2048.0f);
    }
    ushort4 oh, ol;
    oh.x = hh[0]; oh.y = hh[1]; oh.z = hh[2]; oh.w = hh[3];
    ol.x = ll[0]; ol.y = ll[1]; ol.z = ll[2]; ol.w = ll[3];
    *(ushort4*)(WTh + (size_t)(n0 + rr) * K + k0 + c4) = oh;
    *(ushort4*)(WTl + (size_t)(n0 + rr) * K + k0 + c4) = ol;
}

// ---------------------------------------------------------------------------
// f32-accuracy GEMM via 2-way f16 split MFMA (Markidis/Ootomo):
//   C = Ah*Bh + 2^-11*(Ah*Bl' + Al'*Bh),   lo' = (x - hi)*2^11.
// Double-buffered LDS + register prefetch, 1 barrier per K-step.
// ---------------------------------------------------------------------------
template <bool AF32, bool RELU, bool OUTSPLIT>
__global__ __launch_bounds__(256, 2) void gemm_f16x2(
    const float* __restrict__ Af,
    const unsigned short* __restrict__ Ah, const unsigned short* __restrict__ Al,
    const unsigned short* __restrict__ WTh, const unsigned short* __restrict__ WTl,
    const float* __restrict__ bias,
    void* __restrict__ Oh, unsigned short* __restrict__ Ol,
    int M, int N, int K)
{
    __shared__ unsigned short Ash[2][128][36];
    __shared__ unsigned short Asl[2][128][36];
    __shared__ unsigned short Bsh[2][128][36];
    __shared__ unsigned short Bsl[2][128][36];

    const int t = threadIdx.x;
    const int m0 = blockIdx.y * 128, n0 = blockIdx.x * 128;
    const int wave = t >> 6, lane = t & 63;
    const int wm = wave & 1, wn = wave >> 1;
    const int l15 = lane & 15, kq = lane >> 4;

    f32x4 ach[4][4] = {};
    f32x4 acl[4][4] = {};

    const int sr = t >> 1, skc = (t & 1) * 16;

    float af[16];
    uint4 vah, vah2, val, val2;
    uint4 vbh, vbh2, vbl, vbl2;

    auto LOAD = [&](int kb) {
        if (AF32) {
            const float* ap = Af + (size_t)(m0 + sr) * K + kb + skc;
            *(float4*)&af[0]  = *(const float4*)(ap);
            *(float4*)&af[4]  = *(const float4*)(ap + 4);
            *(float4*)&af[8]  = *(const float4*)(ap + 8);
            *(float4*)&af[12] = *(const float4*)(ap + 12);
        } else {
            const unsigned short* aph = Ah + (size_t)(m0 + sr) * K + kb + skc;
            const unsigned short* apl = Al + (size_t)(m0 + sr) * K + kb + skc;
            vah  = *(const uint4*)(aph);
            vah2 = *(const uint4*)(aph + 8);
            val  = *(const uint4*)(apl);
            val2 = *(const uint4*)(apl + 8);
        }
        const unsigned short* bph = WTh + (size_t)(n0 + sr) * K + kb + skc;
        const unsigned short* bpl = WTl + (size_t)(n0 + sr) * K + kb + skc;
        vbh  = *(const uint4*)(bph);
        vbh2 = *(const uint4*)(bph + 8);
        vbl  = *(const uint4*)(bpl);
        vbl2 = *(const uint4*)(bpl + 8);
    };

    auto STORE = [&](int buf) {
        uint4 wah, wah2, wal, wal2;
        if (AF32) {
            split8(&af[0], wah, wal);
            split8(&af[8], wah2, wal2);
        } else {
            wah = vah; wah2 = vah2; wal = val; wal2 = val2;
        }
        *(uint4*)&Ash[buf][sr][skc]     = wah;
        *(uint4*)&Ash[buf][sr][skc + 8] = wah2;
        *(uint4*)&Asl[buf][sr][skc]     = wal;
        *(uint4*)&Asl[buf][sr][skc + 8] = wal2;
        *(uint4*)&Bsh[buf][sr][skc]     = vbh;
        *(uint4*)&Bsh[buf][sr][skc + 8] = vbh2;
        *(uint4*)&Bsl[buf][sr][skc]     = vbl;
        *(uint4*)&Bsl[buf][sr][skc + 8] = vbl2;
    };

    const int nt = K >> 5;
    LOAD(0);
    STORE(0);
    int cur = 0;
    for (int ti = 0; ti < nt; ++ti) {
        __syncthreads();
        if (ti + 1 < nt) LOAD((ti + 1) << 5);

        f16x8 bh[4], bl[4];
#pragma unroll
        for (int bn = 0; bn < 4; ++bn) {
            bh[bn] = *(const f16x8*)&Bsh[cur][wn * 64 + bn * 16 + l15][kq * 8];
            bl[bn] = *(const f16x8*)&Bsl[cur][wn * 64 + bn * 16 + l15][kq * 8];
        }
#pragma unroll
        for (int am = 0; am < 4; ++am) {
            f16x8 ah_ = *(const f16x8*)&Ash[cur][wm * 64 + am * 16 + l15][kq * 8];
            f16x8 al_ = *(const f16x8*)&Asl[cur][wm * 64 + am * 16 + l15][kq * 8];
#pragma unroll
            for (int bn = 0; bn < 4; ++bn) {
                ach[am][bn] = __builtin_amdgcn_mfma_f32_16x16x32_f16(ah_, bh[bn], ach[am][bn], 0, 0, 0);
                acl[am][bn] = __builtin_amdgcn_mfma_f32_16x16x32_f16(ah_, bl[bn], acl[am][bn], 0, 0, 0);
                acl[am][bn] = __builtin_amdgcn_mfma_f32_16x16x32_f16(al_, bh[bn], acl[am][bn], 0, 0, 0);
            }
        }
        if (ti + 1 < nt) STORE(cur ^ 1);
        cur ^= 1;
    }

#pragma unroll
    for (int am = 0; am < 4; ++am)
#pragma unroll
        for (int bn = 0; bn < 4; ++bn)
#pragma unroll
            for (int r = 0; r < 4; ++r) {
                int row = m0 + wm * 64 + am * 16 + kq * 4 + r;
                int col = n0 + wn * 64 + bn * 16 + l15;
                float v = (ach[am][bn][r] + acl[am][bn][r] * (1.0f / 2048.0f))
                          * (1.0f / 32.0f) + bias[col];
                if (RELU) v = fmaxf(v, 0.0f);
                if (OUTSPLIT) {
                    _Float16 hi = (_Float16)v;
                    float hf = (float)hi;
                    ((unsigned short*)Oh)[(size_t)row * N + col] =
                        __builtin_bit_cast(unsigned short, hi);
                    Ol[(size_t)row * N + col] = f2h((v - hf) * 2048.0f);
                } else {
                    ((float*)Oh)[(size_t)row * N + col] = v;
                }
            }
}

// ---------------------------------------------------------------------------
// 128x128 bf16 MFMA GEMM, A[M,K] bf16, WT[N,K] bf16 (pre-transposed).
// Double-buffered LDS + register prefetch.  Decoder layers 1/2/3.
// ---------------------------------------------------------------------------
template <bool RELU, bool OUTF32>
__global__ __launch_bounds__(256) void gemm_bt128(
    const unsigned short* __restrict__ A, const unsigned short* __restrict__ WT,
    const float* __restrict__ bias, void* __restrict__ Ov,
    int M, int N, int K)
{
    __shared__ unsigned short As[2][128][36];
    __shared__ unsigned short Bs[2][128][36];

    const int t = threadIdx.x;
    const int m0 = blockIdx.y * 128, n0 = blockIdx.x * 128;
    const int wave = t >> 6, lane = t & 63;
    const int wm = wave & 1, wn = wave >> 1;
    const int l15 = lane & 15, kq = lane >> 4;

    f32x4 acc[4][4] = {};

    const int sr = t >> 1, skc = (t & 1) * 16;

    uint4 va, va2, vb, vb2;
    auto LOAD = [&](int kb) {
        const unsigned short* ap = A + (size_t)(m0 + sr) * K + kb + skc;
        const unsigned short* bp = WT + (size_t)(n0 + sr) * K + kb + skc;
        va  = *(const uint4*)(ap);
        va2 = *(const uint4*)(ap + 8);
        vb  = *(const uint4*)(bp);
        vb2 = *(const uint4*)(bp + 8);
    };
    auto STORE = [&](int buf) {
        *(uint4*)&As[buf][sr][skc]     = va;
        *(uint4*)&As[buf][sr][skc + 8] = va2;
        *(uint4*)&Bs[buf][sr][skc]     = vb;
        *(uint4*)&Bs[buf][sr][skc + 8] = vb2;
    };

    const int nt = K >> 5;
    LOAD(0);
    STORE(0);
    int cur = 0;
    for (int ti = 0; ti < nt; ++ti) {
        __syncthreads();
        if (ti + 1 < nt) LOAD((ti + 1) << 5);

        bf16x8 bfr[4];
#pragma unroll
        for (int bn = 0; bn < 4; ++bn)
            bfr[bn] = *(const bf16x8*)&Bs[cur][wn * 64 + bn * 16 + l15][kq * 8];
#pragma unroll
        for (int am = 0; am < 4; ++am) {
            bf16x8 af = *(const bf16x8*)&As[cur][wm * 64 + am * 16 + l15][kq * 8];
#pragma unroll
            for (int bn = 0; bn < 4; ++bn)
                acc[am][bn] = __builtin_amdgcn_mfma_f32_16x16x32_bf16(af, bfr[bn], acc[am][bn], 0, 0, 0);
        }
        if (ti + 1 < nt) STORE(cur ^ 1);
        cur ^= 1;
    }

#pragma unroll
    for (int am = 0; am < 4; ++am)
#pragma unroll
        for (int bn = 0; bn < 4; ++bn)
#pragma unroll
            for (int r = 0; r < 4; ++r) {
                int row = m0 + wm * 64 + am * 16 + kq * 4 + r;
                int col = n0 + wn * 64 + bn * 16 + l15;
                float v = acc[am][bn][r] + bias[col];
                if (RELU) v = fmaxf(v, 0.0f);
                if (OUTF32)
                    ((float*)Ov)[(size_t)row * N + col] = v;
                else
                    ((unsigned short*)Ov)[(size_t)row * N + col] = f2bf(v);
            }
}

// ---------------------------------------------------------------------------
// Weight transpose + f32->bf16: W[K,N] f32 -> WT[N,K] bf16 (decoder).
// ---------------------------------------------------------------------------
__global__ __launch_bounds__(256) void wtrans(
    const float* __restrict__ W, unsigned short* __restrict__ WT, int K, int N)
{
    __shared__ unsigned short tile[32][33];
    const int t = threadIdx.x;
    const int n0 = blockIdx.x * 32, k0 = blockIdx.y * 32;
    const int r = t >> 3, c4 = (t & 7) * 4;
    float4 w = *(const float4*)(W + (size_t)(k0 + r) * N + n0 + c4);
    tile[r][c4 + 0] = f2bf(w.x);
    tile[r][c4 + 1] = f2bf(w.y);
    tile[r][c4 + 2] = f2bf(w.z);
    tile[r][c4 + 3] = f2bf(w.w);
    __syncthreads();
    ushort4 o;
    o.x = tile[c4 + 0][r]; o.y = tile[c4 + 1][r];
    o.z = tile[c4 + 2][r]; o.w = tile[c4 + 3][r];
    *(ushort4*)(WT + (size_t)(n0 + r) * K + k0 + c4) = o;
}

// ---------------------------------------------------------------------------
// LayerNorm over D=256, f32 (round-3 exact form).
// ---------------------------------------------------------------------------
__global__ __launch_bounds__(256) void ln_kernel(
    const float* __restrict__ Z, const float* __restrict__ g,
    const float* __restrict__ b, float* __restrict__ R)
{
    int row = blockIdx.x * 4 + (threadIdx.x >> 6);
    int lane = threadIdx.x & 63;
    float4 v = *(const float4*)(Z + (size_t)row * 256 + lane * 4);
    float s = v.x + v.y + v.z + v.w;
#pragma unroll
    for (int o = 32; o; o >>= 1) s += __shfl_xor(s, o);
    float mu = s * (1.0f / 256.0f);
    float4 d = {v.x - mu, v.y - mu, v.z - mu, v.w - mu};
    float q = d.x * d.x + d.y * d.y + d.z * d.z + d.w * d.w;
#pragma unroll
    for (int o = 32; o; o >>= 1) q += __shfl_xor(q, o);
    float var = q * (1.0f / 256.0f);
    float rs = 1.0f / sqrtf(var + 1e-5f);
    int c0 = lane * 4;
    float4 gg = *(const float4*)(g + c0);
    float4 bb = *(const float4*)(b + c0);
    float4 o4;
    o4.x = d.x * rs * gg.x + bb.x;
    o4.y = d.y * rs * gg.y + bb.y;
    o4.z = d.z * rs * gg.z + bb.z;
    o4.w = d.w * rs * gg.w + bb.w;
    *(float4*)(R + (size_t)row * 256 + c0) = o4;
}

// ---------------------------------------------------------------------------
// Fused cn + amin init for all 3 stages.  Per-row fmaf chain identical to
// the original cninit_kernel (argmin-critical).
// cn: [3][1024], amin: [3][16384].  grid 192.
// ---------------------------------------------------------------------------
__global__ __launch_bounds__(256) void cninit3(
    const float* __restrict__ CB0, const float* __restrict__ CB1,
    const float* __restrict__ CB2, float* __restrict__ cn,
    unsigned long long* __restrict__ amin)
{
    int b = blockIdx.x;
    int s = b >> 6, lb = b & 63;
    int g = lb * 256 + threadIdx.x;
    amin[(size_t)s * 16384 + g] = 0xFFFFFFFFFFFFFFFFULL;
    if (g < 1024) {
        const float* CB = (s == 0) ? CB0 : (s == 1) ? CB1 : CB2;
        const float* p = CB + (size_t)g * 256;
        float sum = 0.f;
        for (int d = 0; d < 256; ++d) sum = fmaf(p[d], p[d], sum);
        cn[s * 1024 + g] = sum;
    }
}

__global__ __launch_bounds__(256) void rn_kernel(
    const float* __restrict__ R, float* __restrict__ rn)
{
    __shared__ float rs[16][260];
    const int t = threadIdx.x, r0 = blockIdx.x * 16;
    {
        int row = t >> 4, j = t & 15;
#pragma unroll
        for (int q = 0; q < 4; ++q) {
            int col = j * 16 + q * 4;
            *(float4*)&rs[row][col] = *(const float4*)(R + (size_t)(r0 + row) * 256 + col);
        }
    }
    __syncthreads();
    if (t < 16) {
        float s = 0.f;
        for (int d = 0; d < 256; ++d) s = fmaf(rs[t][d], rs[t][d], s);
        rn[r0 + t] = s;
    }
}

// ---------------------------------------------------------------------------
// VQ distance: f32 fmaf chain EXACTLY as round-3 (argmin-critical).
// Schedule-only change: double-buffered LDS + register prefetch, 1 barrier
// per K-step; red array overlaps the (dead) A/B tiles after an extra barrier.
// ---------------------------------------------------------------------------
__global__ __launch_bounds__(256) void vq_dist(
    const float* __restrict__ Rbuf, const float* __restrict__ CB,
    const float* __restrict__ rn, const float* __restrict__ cn,
    unsigned long long* __restrict__ amin)
{
    __shared__ char smem[33792];                 // As[2]+Bs[2]; red overlaps
    float (*As)[16][132] = (float (*)[16][132])smem;
    float (*Bs)[16][132] = (float (*)[16][132])(smem + 16896);
    unsigned long long (*red)[17] = (unsigned long long (*)[17])smem;

    const int t = threadIdx.x;
    const int m0 = blockIdx.y * 128, n0 = blockIdx.x * 128;
    const int tx = t & 15, ty = t >> 4;
    float c[8][8] = {};

    const int sr = t >> 1, skc = (t & 1) * 8;

    float4 a0, a1, b0, b1;
    auto LOAD = [&](int kb) {
        const float* ap = Rbuf + (size_t)(m0 + sr) * 256 + kb + skc;
        a0 = *(const float4*)(ap);
        a1 = *(const float4*)(ap + 4);
        const float* bp = CB + (size_t)(n0 + sr) * 256 + kb + skc;
        b0 = *(const float4*)(bp);
        b1 = *(const float4*)(bp + 4);
    };
    auto STORE = [&](int buf) {
        As[buf][skc + 0][sr] = a0.x; As[buf][skc + 1][sr] = a0.y;
        As[buf][skc + 2][sr] = a0.z; As[buf][skc + 3][sr] = a0.w;
        As[buf][skc + 4][sr] = a1.x; As[buf][skc + 5][sr] = a1.y;
        As[buf][skc + 6][sr] = a1.z; As[buf][skc + 7][sr] = a1.w;
        Bs[buf][skc + 0][sr] = b0.x; Bs[buf][skc + 1][sr] = b0.y;
        Bs[buf][skc + 2][sr] = b0.z; Bs[buf][skc + 3][sr] = b0.w;
        Bs[buf][skc + 4][sr] = b1.x; Bs[buf][skc + 5][sr] = b1.y;
        Bs[buf][skc + 6][sr] = b1.z; Bs[buf][skc + 7][sr] = b1.w;
    };

    LOAD(0);
    STORE(0);
    int cur = 0;
    for (int ti = 0; ti < 16; ++ti) {
        __syncthreads();
        if (ti + 1 < 16) LOAD((ti + 1) * 16);

#pragma unroll
        for (int k = 0; k < 16; ++k) {
            float a[8], b[8];
            *(float4*)&a[0] = *(const float4*)&As[cur][k][ty * 8];
            *(float4*)&a[4] = *(const float4*)&As[cur][k][ty * 8 + 4];
            *(float4*)&b[0] = *(const float4*)&Bs[cur][k][tx * 4];
            *(float4*)&b[4] = *(const float4*)&Bs[cur][k][64 + tx * 4];
#pragma unroll
            for (int i = 0; i < 8; ++i)
#pragma unroll
                for (int j = 0; j < 8; ++j)
                    c[i][j] = fmaf(a[i], b[j], c[i][j]);
        }
        if (ti + 1 < 16) STORE(cur ^ 1);
        cur ^= 1;
    }

    float rnv[8], cnv[8];
    *(float4*)&rnv[0] = *(const float4*)(rn + m0 + ty * 8);
    *(float4*)&rnv[4] = *(const float4*)(rn + m0 + ty * 8 + 4);
    *(float4*)&cnv[0] = *(const float4*)(cn + n0 + tx * 4);
    *(float4*)&cnv[4] = *(const float4*)(cn + n0 + 64 + tx * 4);

    __syncthreads();   // tiles dead; smem reused as red[128][17]

#pragma unroll
    for (int i = 0; i < 8; ++i) {
        unsigned long long best = 0xFFFFFFFFFFFFFFFFULL;
#pragma unroll
        for (int j = 0; j < 8; ++j) {
            float dist = (rnv[i] - 2.0f * c[i][j]) + cnv[j];
            int col = n0 + (j < 4 ? tx * 4 + j : 64 + tx * 4 + (j - 4));
            unsigned long long p =
                ((unsigned long long)__builtin_bit_cast(unsigned int, dist) << 32) |
                (unsigned int)col;
            if (p < best) best = p;
        }
        red[ty * 8 + i][tx] = best;
    }
    __syncthreads();
    if (t < 128) {
        unsigned long long b = red[t][0];
#pragma unroll
        for (int j = 1; j < 16; ++j) {
            unsigned long long v = red[t][j];
            if (v < b) b = v;
        }
        atomicMin(amin + m0 + t, b);
    }
}

__global__ __launch_bounds__(256) void vq_update(
    float* __restrict__ Rbuf, float* __restrict__ ZQ, float* __restrict__ lossf,
    const float* __restrict__ CB, const unsigned long long* __restrict__ amin,
    float* __restrict__ idx_out, unsigned short* __restrict__ ZQB, int stage)
{
    __shared__ float lred[16][17];
    const int t = threadIdx.x, r0 = blockIdx.x * 16;
    const int row = r0 + (t >> 4), c16 = (t & 15) * 16;
    unsigned int idx = (unsigned int)(amin[row] & 0xffffffffu);
    const float* e = CB + (size_t)idx * 256 + c16;
    float* rp = Rbuf + (size_t)row * 256 + c16;
    float* zp = ZQ + (size_t)row * 256 + c16;
    float part = 0.f;
#pragma unroll
    for (int q = 0; q < 4; ++q) {
        float4 ev = *(const float4*)(e + q * 4);
        float4 rv = *(const float4*)(rp + q * 4);
        float4 dv = {rv.x - ev.x, rv.y - ev.y, rv.z - ev.z, rv.w - ev.w};
        *(float4*)(rp + q * 4) = dv;
        if (stage == 0) {
            *(float4*)(zp + q * 4) = ev;
        } else if (stage == 1) {
            float4 zv = *(const float4*)(zp + q * 4);
            zv.x += ev.x; zv.y += ev.y; zv.z += ev.z; zv.w += ev.w;
            *(float4*)(zp + q * 4) = zv;
        } else {
            // final stage: emit zq directly as bf16 for the decoder
            float4 zv = *(const float4*)(zp + q * 4);
            zv.x += ev.x; zv.y += ev.y; zv.z += ev.z; zv.w += ev.w;
            ushort4 zb;
            zb.x = f2bf(zv.x); zb.y = f2bf(zv.y);
            zb.z = f2bf(zv.z); zb.w = f2bf(zv.w);
            *(ushort4*)(ZQB + (size_t)row * 256 + c16 + q * 4) = zb;
        }
        part = fmaf(dv.x, dv.x, part);
        part = fmaf(dv.y, dv.y, part);
        part = fmaf(dv.z, dv.z, part);
        part = fmaf(dv.w, dv.w, part);
    }
    lred[t >> 4][t & 15] = part;
    __syncthreads();
    if (t < 16) {
        float s = 0.f;
        for (int j = 0; j < 16; ++j) s += lred[t][j];
        float m = s * (1.0f / 256.0f);
        float l = m + BETA * m;
        int gr = r0 + t;
        if (stage == 0) lossf[gr] = l;
        else            lossf[gr] += l;
        idx_out[(size_t)gr * 3 + stage] =
            (float)(unsigned int)(amin[gr] & 0xffffffffu);
    }
}

// ---------------------------------------------------------------------------
// recon loss.
// ---------------------------------------------------------------------------
__global__ __launch_bounds__(256) void recon_kernel(
    const float* __restrict__ XH, const float* __restrict__ X,
    const float* __restrict__ LOSS_IN, float* __restrict__ LOSS_OUT)
{
    __shared__ float wsum[4];
    int row = blockIdx.x, t = threadIdx.x;
    float4 h0 = *(const float4*)(XH + (size_t)row * 2048 + t * 8);
    float4 h1 = *(const float4*)(XH + (size_t)row * 2048 + t * 8 + 4);
    float4 x0 = *(const float4*)(X + (size_t)row * 2048 + t * 8);
    float4 x1 = *(const float4*)(X + (size_t)row * 2048 + t * 8 + 4);
    float h[8] = {h0.x, h0.y, h0.z, h0.w, h1.x, h1.y, h1.z, h1.w};
    float xv[8] = {x0.x, x0.y, x0.z, x0.w, x1.x, x1.y, x1.z, x1.w};
    float s = 0.f;
#pragma unroll
    for (int j = 0; j < 8; ++j) {
        float d = h[j] - xv[j];
        s = fmaf(d, d, s);
    }
#pragma unroll
    for (int o = 32; o; o >>= 1) s += __shfl_xor(s, o);
    if ((t & 63) == 0) wsum[t >> 6] = s;
    __syncthreads();
    if (t == 0) {
        float tot = wsum[0] + wsum[1] + wsum[2] + wsum[3];
        LOSS_OUT[row] = LOSS_IN[row] + tot * (1.0f / 2048.0f);
    }
}

// ---------------------------------------------------------------------------
extern "C" void kernel_launch(void* const* d_in, const int* in_sizes, int n_in,
                              void* d_out, int out_size, void* d_ws, size_t ws_size,
                              hipStream_t stream)
{
    const float* x      = (const float*)d_in[0];
    const float* enc_W1 = (const float*)d_in[1];
    const float* enc_b1 = (const float*)d_in[2];
    const float* enc_W2 = (const float*)d_in[3];
    const float* enc_b2 = (const float*)d_in[4];
    const float* enc_W3 = (const float*)d_in[5];
    const float* enc_b3 = (const float*)d_in[6];
    const float* ln_g   = (const float*)d_in[7];
    const float* ln_b   = (const float*)d_in[8];
    const float* cb0    = (const float*)d_in[9];
    const float* cb1    = (const float*)d_in[10];
    const float* cb2    = (const float*)d_in[11];
    const float* dec_W1 = (const float*)d_in[12];
    const float* dec_b1 = (const float*)d_in[13];
    const float* dec_W2 = (const float*)d_in[14];
    const float* dec_b2 = (const float*)d_in[15];
    const float* dec_W3 = (const float*)d_in[16];
    const float* dec_b3 = (const float*)d_in[17];

    const int B = 16384, D_IN = 2048, H1 = 1024, H2 = 512, D_LAT = 256;

    // workspace overlays (<= 128 MB):
    //   [0,64M)    h1h/h1l f16 (dead after enc G2)
    //              -> decoder: d1 [0,16M), d2 [16,48M), WT3 [48,52M), WT2 [52,53M)
    //   [64,96M)   h2h/h2l f16 (dead after enc G3) ->
    //              lossf 64M, cn[3][1024] 65M, amin[3][16384] 66M (384KB),
    //              rn 67M, zqb [68,76M), wt1 76M (256KB)
    //   [96,112M)  z f32 (dead after LN -> zq); before G3: W1T/W2T splits
    //   [112,128M) r f32 (written by LN); before LN: W3T splits at 112M/113M
    char* ws = (char*)d_ws;
    unsigned short* h1h = (unsigned short*)(ws);
    unsigned short* h1l = (unsigned short*)(ws + (32u << 20));
    unsigned short* h2h = (unsigned short*)(ws + (64u << 20));
    unsigned short* h2l = (unsigned short*)(ws + (80u << 20));
    float* z     = (float*)(ws + (96u << 20));
    float* r     = (float*)(ws + (112u << 20));
    float* zq    = (float*)(ws + (96u << 20));
    unsigned short* w1th = (unsigned short*)(ws + (96u << 20));    // 4MB
    unsigned short* w1tl = (unsigned short*)(ws + (100u << 20));   // 4MB
    unsigned short* w2th = (unsigned short*)(ws + (104u << 20));   // 1MB
    unsigned short* w2tl = (unsigned short*)(ws + (105u << 20));   // 1MB
    unsigned short* w3th = (unsigned short*)(ws + (112u << 20));   // 256KB (in r, dead before LN)
    unsigned short* w3tl = (unsigned short*)(ws + (113u << 20));   // 256KB
    unsigned short* d1  = (unsigned short*)(ws);
    unsigned short* d2  = (unsigned short*)(ws + (16u << 20));
    unsigned short* wt3 = (unsigned short*)(ws + (48u << 20));
    unsigned short* wt2 = (unsigned short*)(ws + (52u << 20));
    float* lossf = (float*)(ws + (64u << 20));
    float* cn3   = (float*)(ws + (65u << 20));
    unsigned long long* amin3 = (unsigned long long*)(ws + (66u << 20));
    float* rnb   = (float*)(ws + (67u << 20));
    unsigned short* zqb = (unsigned short*)(ws + (68u << 20));     // 8MB
    unsigned short* wt1 = (unsigned short*)(ws + (76u << 20));     // 256KB

    float* xhat     = (float*)d_out;
    float* loss_out = xhat + (size_t)B * D_IN;
    float* idx_out  = loss_out + B;

    // encoder weight split+transpose (f16 hi/lo, x32 scaled)
    wsplit_t<<<dim3(H1 / 32, D_IN / 32), 256, 0, stream>>>(enc_W1, w1th, w1tl, D_IN, H1);
    wsplit_t<<<dim3(H2 / 32, H1 / 32), 256, 0, stream>>>(enc_W2, w2th, w2tl, H1, H2);
    wsplit_t<<<dim3(D_LAT / 32, H2 / 32), 256, 0, stream>>>(enc_W3, w3th, w3tl, H2, D_LAT);

    // encoder: f32-accuracy split-f16 MFMA GEMMs (pipelined)
    gemm_f16x2<true, true, true><<<dim3(H1 / 128, B / 128), 256, 0, stream>>>(
        x, nullptr, nullptr, w1th, w1tl, enc_b1, h1h, h1l, B, H1, D_IN);
    gemm_f16x2<false, true, true><<<dim3(H2 / 128, B / 128), 256, 0, stream>>>(
        nullptr, h1h, h1l, w2th, w2tl, enc_b2, h2h, h2l, B, H2, H1);
    // decoder weight prep (h1 region partially dead now; wt2/wt3 live in h1l)
    wtrans<<<dim3(H1 / 32, H2 / 32), 256, 0, stream>>>(dec_W2, wt2, H2, H1);
    wtrans<<<dim3(D_IN / 32, H1 / 32), 256, 0, stream>>>(dec_W3, wt3, H1, D_IN);
    gemm_f16x2<false, false, false><<<dim3(D_LAT / 128, B / 128), 256, 0, stream>>>(
        nullptr, h2h, h2l, w3th, w3tl, enc_b3, z, nullptr, B, D_LAT, H2);
    ln_kernel<<<B / 4, 256, 0, stream>>>(z, ln_g, ln_b, r);

    // h2 region dead after G3: cn/amin for all 3 stages + dec_W1 transpose
    cninit3<<<192, 256, 0, stream>>>(cb0, cb1, cb2, cn3, amin3);
    wtrans<<<dim3(H2 / 32, D_LAT / 32), 256, 0, stream>>>(dec_W1, wt1, D_LAT, H2);

    // residual VQ (f32 argmin-exact path; vq_dist pipelined, same math)
    const float* cbs[3] = {cb0, cb1, cb2};
    for (int s = 0; s < 3; ++s) {
        rn_kernel<<<B / 16, 256, 0, stream>>>(r, rnb);
        vq_dist<<<dim3(1024 / 128, B / 128), 256, 0, stream>>>(
            r, cbs[s], rnb, cn3 + s * 1024, amin3 + (size_t)s * 16384);
        vq_update<<<B / 16, 256, 0, stream>>>(
            r, zq, lossf, cbs[s], amin3 + (size_t)s * 16384, idx_out, zqb, s);
    }

    // decoder (all 128x128 pipelined bf16 MFMA)
    gemm_bt128<true, false><<<dim3(H2 / 128, B / 128), 256, 0, stream>>>(
        zqb, wt1, dec_b1, d1, B, H2, D_LAT);
    gemm_bt128<true, false><<<dim3(H1 / 128, B / 128), 256, 0, stream>>>(
        d1, wt2, dec_b2, d2, B, H1, H2);
    gemm_bt128<false, true><<<dim3(D_IN / 128, B / 128), 256, 0, stream>>>(
        d2, wt3, dec_b3, xhat, B, D_IN, H1);
    recon_kernel<<<B, 256, 0, stream>>>(xhat, x, lossf, loss_out);
}

// Round 8
// 1167.480 us; speedup vs baseline: 1.1396x; 1.1396x over previous
//
#include <hip/hip_runtime.h>
#include <stdint.h>

typedef __bf16 bf16x8 __attribute__((ext_vector_type(8)));
typedef _Float16 f16x8 __attribute__((ext_vector_type(8)));
typedef float f32x4 __attribute__((ext_vector_type(4)));

#define BETA 0.25f

__device__ __forceinline__ unsigned short f2bf(float f) {
    __bf16 h = (__bf16)f;
    return __builtin_bit_cast(unsigned short, h);
}

__device__ __forceinline__ unsigned short f2h(float f) {
    _Float16 h = (_Float16)f;
    return __builtin_bit_cast(unsigned short, h);
}

// Split 8 f32 -> f16 hi + f16 lo*2^11, packed as uint4 each.
__device__ __forceinline__ void split8(const float* a, uint4& vh, uint4& vl) {
    unsigned h[8], l[8];
#pragma unroll
    for (int j = 0; j < 8; ++j) {
        _Float16 hi = (_Float16)a[j];
        float hf = (float)hi;
        _Float16 lo = (_Float16)((a[j] - hf) * 2048.0f);
        h[j] = (unsigned)__builtin_bit_cast(unsigned short, hi);
        l[j] = (unsigned)__builtin_bit_cast(unsigned short, lo);
    }
    vh.x = h[0] | (h[1] << 16); vh.y = h[2] | (h[3] << 16);
    vh.z = h[4] | (h[5] << 16); vh.w = h[6] | (h[7] << 16);
    vl.x = l[0] | (l[1] << 16); vl.y = l[2] | (l[3] << 16);
    vl.z = l[4] | (l[5] << 16); vl.w = l[6] | (l[7] << 16);
}

// ---------------------------------------------------------------------------
// Weight split + transpose: W[K,N] f32 -> WTh,WTl [N,K] f16 (x32 scaled).
// ---------------------------------------------------------------------------
__global__ __launch_bounds__(256) void wsplit_t(
    const float* __restrict__ W, unsigned short* __restrict__ WTh,
    unsigned short* __restrict__ WTl, int K, int N)
{
    __shared__ float tile[32][33];
    const int t = threadIdx.x;
    const int n0 = blockIdx.x * 32, k0 = blockIdx.y * 32;
    const int rr = t >> 3, c4 = (t & 7) * 4;
    float4 w = *(const float4*)(W + (size_t)(k0 + rr) * N + n0 + c4);
    tile[rr][c4 + 0] = w.x; tile[rr][c4 + 1] = w.y;
    tile[rr][c4 + 2] = w.z; tile[rr][c4 + 3] = w.w;
    __syncthreads();
    float v[4] = {tile[c4 + 0][rr], tile[c4 + 1][rr],
                  tile[c4 + 2][rr], tile[c4 + 3][rr]};
    unsigned short hh[4], ll[4];
#pragma unroll
    for (int j = 0; j < 4; ++j) {
        float s = v[j] * 32.0f;
        _Float16 hi = (_Float16)s;
        float hf = (float)hi;
        hh[j] = __builtin_bit_cast(unsigned short, hi);
        ll[j] = f2h((s - hf) * 2048.0f);
    }
    ushort4 oh, ol;
    oh.x = hh[0]; oh.y = hh[1]; oh.z = hh[2]; oh.w = hh[3];
    ol.x = ll[0]; ol.y = ll[1]; ol.z = ll[2]; ol.w = ll[3];
    *(ushort4*)(WTh + (size_t)(n0 + rr) * K + k0 + c4) = oh;
    *(ushort4*)(WTl + (size_t)(n0 + rr) * K + k0 + c4) = ol;
}

// ---------------------------------------------------------------------------
// f32-accuracy GEMM via 2-way f16 split MFMA (Markidis/Ootomo):
//   C = Ah*Bh + 2^-11*(Ah*Bl' + Al'*Bh),   lo' = (x - hi)*2^11.
// Double-buffered LDS + register prefetch, 1 barrier per K-step.
// ---------------------------------------------------------------------------
template <bool AF32, bool RELU, bool OUTSPLIT>
__global__ __launch_bounds__(256, 2) void gemm_f16x2(
    const float* __restrict__ Af,
    const unsigned short* __restrict__ Ah, const unsigned short* __restrict__ Al,
    const unsigned short* __restrict__ WTh, const unsigned short* __restrict__ WTl,
    const float* __restrict__ bias,
    void* __restrict__ Oh, unsigned short* __restrict__ Ol,
    int M, int N, int K)
{
    __shared__ unsigned short Ash[2][128][36];
    __shared__ unsigned short Asl[2][128][36];
    __shared__ unsigned short Bsh[2][128][36];
    __shared__ unsigned short Bsl[2][128][36];

    const int t = threadIdx.x;
    const int m0 = blockIdx.y * 128, n0 = blockIdx.x * 128;
    const int wave = t >> 6, lane = t & 63;
    const int wm = wave & 1, wn = wave >> 1;
    const int l15 = lane & 15, kq = lane >> 4;

    f32x4 ach[4][4] = {};
    f32x4 acl[4][4] = {};

    const int sr = t >> 1, skc = (t & 1) * 16;

    float af[16];
    uint4 vah, vah2, val, val2;
    uint4 vbh, vbh2, vbl, vbl2;

    auto LOAD = [&](int kb) {
        if (AF32) {
            const float* ap = Af + (size_t)(m0 + sr) * K + kb + skc;
            *(float4*)&af[0]  = *(const float4*)(ap);
            *(float4*)&af[4]  = *(const float4*)(ap + 4);
            *(float4*)&af[8]  = *(const float4*)(ap + 8);
            *(float4*)&af[12] = *(const float4*)(ap + 12);
        } else {
            const unsigned short* aph = Ah + (size_t)(m0 + sr) * K + kb + skc;
            const unsigned short* apl = Al + (size_t)(m0 + sr) * K + kb + skc;
            vah  = *(const uint4*)(aph);
            vah2 = *(const uint4*)(aph + 8);
            val  = *(const uint4*)(apl);
            val2 = *(const uint4*)(apl + 8);
        }
        const unsigned short* bph = WTh + (size_t)(n0 + sr) * K + kb + skc;
        const unsigned short* bpl = WTl + (size_t)(n0 + sr) * K + kb + skc;
        vbh  = *(const uint4*)(bph);
        vbh2 = *(const uint4*)(bph + 8);
        vbl  = *(const uint4*)(bpl);
        vbl2 = *(const uint4*)(bpl + 8);
    };

    auto STORE = [&](int buf) {
        uint4 wah, wah2, wal, wal2;
        if (AF32) {
            split8(&af[0], wah, wal);
            split8(&af[8], wah2, wal2);
        } else {
            wah = vah; wah2 = vah2; wal = val; wal2 = val2;
        }
        *(uint4*)&Ash[buf][sr][skc]     = wah;
        *(uint4*)&Ash[buf][sr][skc + 8] = wah2;
        *(uint4*)&Asl[buf][sr][skc]     = wal;
        *(uint4*)&Asl[buf][sr][skc + 8] = wal2;
        *(uint4*)&Bsh[buf][sr][skc]     = vbh;
        *(uint4*)&Bsh[buf][sr][skc + 8] = vbh2;
        *(uint4*)&Bsl[buf][sr][skc]     = vbl;
        *(uint4*)&Bsl[buf][sr][skc + 8] = vbl2;
    };

    const int nt = K >> 5;
    LOAD(0);
    STORE(0);
    int cur = 0;
    for (int ti = 0; ti < nt; ++ti) {
        __syncthreads();
        if (ti + 1 < nt) LOAD((ti + 1) << 5);

        f16x8 bh[4], bl[4];
#pragma unroll
        for (int bn = 0; bn < 4; ++bn) {
            bh[bn] = *(const f16x8*)&Bsh[cur][wn * 64 + bn * 16 + l15][kq * 8];
            bl[bn] = *(const f16x8*)&Bsl[cur][wn * 64 + bn * 16 + l15][kq * 8];
        }
#pragma unroll
        for (int am = 0; am < 4; ++am) {
            f16x8 ah_ = *(const f16x8*)&Ash[cur][wm * 64 + am * 16 + l15][kq * 8];
            f16x8 al_ = *(const f16x8*)&Asl[cur][wm * 64 + am * 16 + l15][kq * 8];
#pragma unroll
            for (int bn = 0; bn < 4; ++bn) {
                ach[am][bn] = __builtin_amdgcn_mfma_f32_16x16x32_f16(ah_, bh[bn], ach[am][bn], 0, 0, 0);
                acl[am][bn] = __builtin_amdgcn_mfma_f32_16x16x32_f16(ah_, bl[bn], acl[am][bn], 0, 0, 0);
                acl[am][bn] = __builtin_amdgcn_mfma_f32_16x16x32_f16(al_, bh[bn], acl[am][bn], 0, 0, 0);
            }
        }
        if (ti + 1 < nt) STORE(cur ^ 1);
        cur ^= 1;
    }

#pragma unroll
    for (int am = 0; am < 4; ++am)
#pragma unroll
        for (int bn = 0; bn < 4; ++bn)
#pragma unroll
            for (int r = 0; r < 4; ++r) {
                int row = m0 + wm * 64 + am * 16 + kq * 4 + r;
                int col = n0 + wn * 64 + bn * 16 + l15;
                float v = (ach[am][bn][r] + acl[am][bn][r] * (1.0f / 2048.0f))
                          * (1.0f / 32.0f) + bias[col];
                if (RELU) v = fmaxf(v, 0.0f);
                if (OUTSPLIT) {
                    _Float16 hi = (_Float16)v;
                    float hf = (float)hi;
                    ((unsigned short*)Oh)[(size_t)row * N + col] =
                        __builtin_bit_cast(unsigned short, hi);
                    Ol[(size_t)row * N + col] = f2h((v - hf) * 2048.0f);
                } else {
                    ((float*)Oh)[(size_t)row * N + col] = v;
                }
            }
}

// ---------------------------------------------------------------------------
// 128x128 bf16 MFMA GEMM, A[M,K] bf16, WT[N,K] bf16 (pre-transposed).
// Double-buffered LDS + register prefetch.  Decoder layers 1/2/3.
// ---------------------------------------------------------------------------
template <bool RELU, bool OUTF32>
__global__ __launch_bounds__(256) void gemm_bt128(
    const unsigned short* __restrict__ A, const unsigned short* __restrict__ WT,
    const float* __restrict__ bias, void* __restrict__ Ov,
    int M, int N, int K)
{
    __shared__ unsigned short As[2][128][36];
    __shared__ unsigned short Bs[2][128][36];

    const int t = threadIdx.x;
    const int m0 = blockIdx.y * 128, n0 = blockIdx.x * 128;
    const int wave = t >> 6, lane = t & 63;
    const int wm = wave & 1, wn = wave >> 1;
    const int l15 = lane & 15, kq = lane >> 4;

    f32x4 acc[4][4] = {};

    const int sr = t >> 1, skc = (t & 1) * 16;

    uint4 va, va2, vb, vb2;
    auto LOAD = [&](int kb) {
        const unsigned short* ap = A + (size_t)(m0 + sr) * K + kb + skc;
        const unsigned short* bp = WT + (size_t)(n0 + sr) * K + kb + skc;
        va  = *(const uint4*)(ap);
        va2 = *(const uint4*)(ap + 8);
        vb  = *(const uint4*)(bp);
        vb2 = *(const uint4*)(bp + 8);
    };
    auto STORE = [&](int buf) {
        *(uint4*)&As[buf][sr][skc]     = va;
        *(uint4*)&As[buf][sr][skc + 8] = va2;
        *(uint4*)&Bs[buf][sr][skc]     = vb;
        *(uint4*)&Bs[buf][sr][skc + 8] = vb2;
    };

    const int nt = K >> 5;
    LOAD(0);
    STORE(0);
    int cur = 0;
    for (int ti = 0; ti < nt; ++ti) {
        __syncthreads();
        if (ti + 1 < nt) LOAD((ti + 1) << 5);

        bf16x8 bfr[4];
#pragma unroll
        for (int bn = 0; bn < 4; ++bn)
            bfr[bn] = *(const bf16x8*)&Bs[cur][wn * 64 + bn * 16 + l15][kq * 8];
#pragma unroll
        for (int am = 0; am < 4; ++am) {
            bf16x8 af = *(const bf16x8*)&As[cur][wm * 64 + am * 16 + l15][kq * 8];
#pragma unroll
            for (int bn = 0; bn < 4; ++bn)
                acc[am][bn] = __builtin_amdgcn_mfma_f32_16x16x32_bf16(af, bfr[bn], acc[am][bn], 0, 0, 0);
        }
        if (ti + 1 < nt) STORE(cur ^ 1);
        cur ^= 1;
    }

#pragma unroll
    for (int am = 0; am < 4; ++am)
#pragma unroll
        for (int bn = 0; bn < 4; ++bn)
#pragma unroll
            for (int r = 0; r < 4; ++r) {
                int row = m0 + wm * 64 + am * 16 + kq * 4 + r;
                int col = n0 + wn * 64 + bn * 16 + l15;
                float v = acc[am][bn][r] + bias[col];
                if (RELU) v = fmaxf(v, 0.0f);
                if (OUTF32)
                    ((float*)Ov)[(size_t)row * N + col] = v;
                else
                    ((unsigned short*)Ov)[(size_t)row * N + col] = f2bf(v);
            }
}

// ---------------------------------------------------------------------------
// Weight transpose + f32->bf16: W[K,N] f32 -> WT[N,K] bf16 (decoder).
// ---------------------------------------------------------------------------
__global__ __launch_bounds__(256) void wtrans(
    const float* __restrict__ W, unsigned short* __restrict__ WT, int K, int N)
{
    __shared__ unsigned short tile[32][33];
    const int t = threadIdx.x;
    const int n0 = blockIdx.x * 32, k0 = blockIdx.y * 32;
    const int r = t >> 3, c4 = (t & 7) * 4;
    float4 w = *(const float4*)(W + (size_t)(k0 + r) * N + n0 + c4);
    tile[r][c4 + 0] = f2bf(w.x);
    tile[r][c4 + 1] = f2bf(w.y);
    tile[r][c4 + 2] = f2bf(w.z);
    tile[r][c4 + 3] = f2bf(w.w);
    __syncthreads();
    ushort4 o;
    o.x = tile[c4 + 0][r]; o.y = tile[c4 + 1][r];
    o.z = tile[c4 + 2][r]; o.w = tile[c4 + 3][r];
    *(ushort4*)(WT + (size_t)(n0 + r) * K + k0 + c4) = o;
}

// ---------------------------------------------------------------------------
// LayerNorm over D=256, f32 (round-3 exact form).
// ---------------------------------------------------------------------------
__global__ __launch_bounds__(256) void ln_kernel(
    const float* __restrict__ Z, const float* __restrict__ g,
    const float* __restrict__ b, float* __restrict__ R)
{
    int row = blockIdx.x * 4 + (threadIdx.x >> 6);
    int lane = threadIdx.x & 63;
    float4 v = *(const float4*)(Z + (size_t)row * 256 + lane * 4);
    float s = v.x + v.y + v.z + v.w;
#pragma unroll
    for (int o = 32; o; o >>= 1) s += __shfl_xor(s, o);
    float mu = s * (1.0f / 256.0f);
    float4 d = {v.x - mu, v.y - mu, v.z - mu, v.w - mu};
    float q = d.x * d.x + d.y * d.y + d.z * d.z + d.w * d.w;
#pragma unroll
    for (int o = 32; o; o >>= 1) q += __shfl_xor(q, o);
    float var = q * (1.0f / 256.0f);
    float rs = 1.0f / sqrtf(var + 1e-5f);
    int c0 = lane * 4;
    float4 gg = *(const float4*)(g + c0);
    float4 bb = *(const float4*)(b + c0);
    float4 o4;
    o4.x = d.x * rs * gg.x + bb.x;
    o4.y = d.y * rs * gg.y + bb.y;
    o4.z = d.z * rs * gg.z + bb.z;
    o4.w = d.w * rs * gg.w + bb.w;
    *(float4*)(R + (size_t)row * 256 + c0) = o4;
}

// ---------------------------------------------------------------------------
// Fused cn + amin init for all 3 stages.  Per-row fmaf chain identical to
// the original cninit_kernel (argmin-critical).
// cn: [3][1024], amin: [3][16384].  grid 192.
// ---------------------------------------------------------------------------
__global__ __launch_bounds__(256) void cninit3(
    const float* __restrict__ CB0, const float* __restrict__ CB1,
    const float* __restrict__ CB2, float* __restrict__ cn,
    unsigned long long* __restrict__ amin)
{
    int b = blockIdx.x;
    int s = b >> 6, lb = b & 63;
    int g = lb * 256 + threadIdx.x;
    amin[(size_t)s * 16384 + g] = 0xFFFFFFFFFFFFFFFFULL;
    if (g < 1024) {
        const float* CB = (s == 0) ? CB0 : (s == 1) ? CB1 : CB2;
        const float* p = CB + (size_t)g * 256;
        float sum = 0.f;
        for (int d = 0; d < 256; ++d) sum = fmaf(p[d], p[d], sum);
        cn[s * 1024 + g] = sum;
    }
}

__global__ __launch_bounds__(256) void rn_kernel(
    const float* __restrict__ R, float* __restrict__ rn)
{
    __shared__ float rs[16][260];
    const int t = threadIdx.x, r0 = blockIdx.x * 16;
    {
        int row = t >> 4, j = t & 15;
#pragma unroll
        for (int q = 0; q < 4; ++q) {
            int col = j * 16 + q * 4;
            *(float4*)&rs[row][col] = *(const float4*)(R + (size_t)(r0 + row) * 256 + col);
        }
    }
    __syncthreads();
    if (t < 16) {
        float s = 0.f;
        for (int d = 0; d < 256; ++d) s = fmaf(rs[t][d], rs[t][d], s);
        rn[r0 + t] = s;
    }
}

// ---------------------------------------------------------------------------
// VQ distance: round-3 EXACT version (single-buffered, compile-time LDS
// offsets).  Reverted from round-7's pipelined variant for attribution.
// ---------------------------------------------------------------------------
__global__ __launch_bounds__(256) void vq_dist(
    const float* __restrict__ Rbuf, const float* __restrict__ CB,
    const float* __restrict__ rn, const float* __restrict__ cn,
    unsigned long long* __restrict__ amin)
{
    __shared__ float As[16][132];   // [k][m]
    __shared__ float Bs[16][132];   // [k][code]
    __shared__ unsigned long long red[128][17];

    const int t = threadIdx.x;
    const int m0 = blockIdx.y * 128, n0 = blockIdx.x * 128;
    const int tx = t & 15, ty = t >> 4;
    float c[8][8] = {};

    const int sr = t >> 1, skc = (t & 1) * 8;

    for (int kb = 0; kb < 256; kb += 16) {
        const float* ap = Rbuf + (size_t)(m0 + sr) * 256 + kb + skc;
        float4 a0 = *(const float4*)(ap);
        float4 a1 = *(const float4*)(ap + 4);
        const float* bp = CB + (size_t)(n0 + sr) * 256 + kb + skc;
        float4 b0 = *(const float4*)(bp);
        float4 b1 = *(const float4*)(bp + 4);

        __syncthreads();
        As[skc + 0][sr] = a0.x; As[skc + 1][sr] = a0.y;
        As[skc + 2][sr] = a0.z; As[skc + 3][sr] = a0.w;
        As[skc + 4][sr] = a1.x; As[skc + 5][sr] = a1.y;
        As[skc + 6][sr] = a1.z; As[skc + 7][sr] = a1.w;
        Bs[skc + 0][sr] = b0.x; Bs[skc + 1][sr] = b0.y;
        Bs[skc + 2][sr] = b0.z; Bs[skc + 3][sr] = b0.w;
        Bs[skc + 4][sr] = b1.x; Bs[skc + 5][sr] = b1.y;
        Bs[skc + 6][sr] = b1.z; Bs[skc + 7][sr] = b1.w;
        __syncthreads();

#pragma unroll
        for (int k = 0; k < 16; ++k) {
            float a[8], b[8];
            *(float4*)&a[0] = *(const float4*)&As[k][ty * 8];
            *(float4*)&a[4] = *(const float4*)&As[k][ty * 8 + 4];
            *(float4*)&b[0] = *(const float4*)&Bs[k][tx * 4];
            *(float4*)&b[4] = *(const float4*)&Bs[k][64 + tx * 4];
#pragma unroll
            for (int i = 0; i < 8; ++i)
#pragma unroll
                for (int j = 0; j < 8; ++j)
                    c[i][j] = fmaf(a[i], b[j], c[i][j]);
        }
    }

    float rnv[8], cnv[8];
    *(float4*)&rnv[0] = *(const float4*)(rn + m0 + ty * 8);
    *(float4*)&rnv[4] = *(const float4*)(rn + m0 + ty * 8 + 4);
    *(float4*)&cnv[0] = *(const float4*)(cn + n0 + tx * 4);
    *(float4*)&cnv[4] = *(const float4*)(cn + n0 + 64 + tx * 4);

#pragma unroll
    for (int i = 0; i < 8; ++i) {
        unsigned long long best = 0xFFFFFFFFFFFFFFFFULL;
#pragma unroll
        for (int j = 0; j < 8; ++j) {
            float dist = (rnv[i] - 2.0f * c[i][j]) + cnv[j];
            int col = n0 + (j < 4 ? tx * 4 + j : 64 + tx * 4 + (j - 4));
            unsigned long long p =
                ((unsigned long long)__builtin_bit_cast(unsigned int, dist) << 32) |
                (unsigned int)col;
            if (p < best) best = p;
        }
        red[ty * 8 + i][tx] = best;
    }
    __syncthreads();
    if (t < 128) {
        unsigned long long b = red[t][0];
#pragma unroll
        for (int j = 1; j < 16; ++j) {
            unsigned long long v = red[t][j];
            if (v < b) b = v;
        }
        atomicMin(amin + m0 + t, b);
    }
}

__global__ __launch_bounds__(256) void vq_update(
    float* __restrict__ Rbuf, float* __restrict__ ZQ, float* __restrict__ lossf,
    const float* __restrict__ CB, const unsigned long long* __restrict__ amin,
    float* __restrict__ idx_out, unsigned short* __restrict__ ZQB, int stage)
{
    __shared__ float lred[16][17];
    const int t = threadIdx.x, r0 = blockIdx.x * 16;
    const int row = r0 + (t >> 4), c16 = (t & 15) * 16;
    unsigned int idx = (unsigned int)(amin[row] & 0xffffffffu);
    const float* e = CB + (size_t)idx * 256 + c16;
    float* rp = Rbuf + (size_t)row * 256 + c16;
    float* zp = ZQ + (size_t)row * 256 + c16;
    float part = 0.f;
#pragma unroll
    for (int q = 0; q < 4; ++q) {
        float4 ev = *(const float4*)(e + q * 4);
        float4 rv = *(const float4*)(rp + q * 4);
        float4 dv = {rv.x - ev.x, rv.y - ev.y, rv.z - ev.z, rv.w - ev.w};
        *(float4*)(rp + q * 4) = dv;
        if (stage == 0) {
            *(float4*)(zp + q * 4) = ev;
        } else if (stage == 1) {
            float4 zv = *(const float4*)(zp + q * 4);
            zv.x += ev.x; zv.y += ev.y; zv.z += ev.z; zv.w += ev.w;
            *(float4*)(zp + q * 4) = zv;
        } else {
            // final stage: emit zq directly as bf16 for the decoder
            float4 zv = *(const float4*)(zp + q * 4);
            zv.x += ev.x; zv.y += ev.y; zv.z += ev.z; zv.w += ev.w;
            ushort4 zb;
            zb.x = f2bf(zv.x); zb.y = f2bf(zv.y);
            zb.z = f2bf(zv.z); zb.w = f2bf(zv.w);
            *(ushort4*)(ZQB + (size_t)row * 256 + c16 + q * 4) = zb;
        }
        part = fmaf(dv.x, dv.x, part);
        part = fmaf(dv.y, dv.y, part);
        part = fmaf(dv.z, dv.z, part);
        part = fmaf(dv.w, dv.w, part);
    }
    lred[t >> 4][t & 15] = part;
    __syncthreads();
    if (t < 16) {
        float s = 0.f;
        for (int j = 0; j < 16; ++j) s += lred[t][j];
        float m = s * (1.0f / 256.0f);
        float l = m + BETA * m;
        int gr = r0 + t;
        if (stage == 0) lossf[gr] = l;
        else            lossf[gr] += l;
        idx_out[(size_t)gr * 3 + stage] =
            (float)(unsigned int)(amin[gr] & 0xffffffffu);
    }
}

// ---------------------------------------------------------------------------
// recon loss.
// ---------------------------------------------------------------------------
__global__ __launch_bounds__(256) void recon_kernel(
    const float* __restrict__ XH, const float* __restrict__ X,
    const float* __restrict__ LOSS_IN, float* __restrict__ LOSS_OUT)
{
    __shared__ float wsum[4];
    int row = blockIdx.x, t = threadIdx.x;
    float4 h0 = *(const float4*)(XH + (size_t)row * 2048 + t * 8);
    float4 h1 = *(const float4*)(XH + (size_t)row * 2048 + t * 8 + 4);
    float4 x0 = *(const float4*)(X + (size_t)row * 2048 + t * 8);
    float4 x1 = *(const float4*)(X + (size_t)row * 2048 + t * 8 + 4);
    float h[8] = {h0.x, h0.y, h0.z, h0.w, h1.x, h1.y, h1.z, h1.w};
    float xv[8] = {x0.x, x0.y, x0.z, x0.w, x1.x, x1.y, x1.z, x1.w};
    float s = 0.f;
#pragma unroll
    for (int j = 0; j < 8; ++j) {
        float d = h[j] - xv[j];
        s = fmaf(d, d, s);
    }
#pragma unroll
    for (int o = 32; o; o >>= 1) s += __shfl_xor(s, o);
    if ((t & 63) == 0) wsum[t >> 6] = s;
    __syncthreads();
    if (t == 0) {
        float tot = wsum[0] + wsum[1] + wsum[2] + wsum[3];
        LOSS_OUT[row] = LOSS_IN[row] + tot * (1.0f / 2048.0f);
    }
}

// ---------------------------------------------------------------------------
extern "C" void kernel_launch(void* const* d_in, const int* in_sizes, int n_in,
                              void* d_out, int out_size, void* d_ws, size_t ws_size,
                              hipStream_t stream)
{
    const float* x      = (const float*)d_in[0];
    const float* enc_W1 = (const float*)d_in[1];
    const float* enc_b1 = (const float*)d_in[2];
    const float* enc_W2 = (const float*)d_in[3];
    const float* enc_b2 = (const float*)d_in[4];
    const float* enc_W3 = (const float*)d_in[5];
    const float* enc_b3 = (const float*)d_in[6];
    const float* ln_g   = (const float*)d_in[7];
    const float* ln_b   = (const float*)d_in[8];
    const float* cb0    = (const float*)d_in[9];
    const float* cb1    = (const float*)d_in[10];
    const float* cb2    = (const float*)d_in[11];
    const float* dec_W1 = (const float*)d_in[12];
    const float* dec_b1 = (const float*)d_in[13];
    const float* dec_W2 = (const float*)d_in[14];
    const float* dec_b2 = (const float*)d_in[15];
    const float* dec_W3 = (const float*)d_in[16];
    const float* dec_b3 = (const float*)d_in[17];

    const int B = 16384, D_IN = 2048, H1 = 1024, H2 = 512, D_LAT = 256;

    // workspace overlays (<= 128 MB):
    //   [0,64M)    h1h/h1l f16 (dead after enc G2)
    //              -> decoder: d1 [0,16M), d2 [16,48M), WT3 [48,52M), WT2 [52,53M)
    //   [64,96M)   h2h/h2l f16 (dead after enc G3) ->
    //              lossf 64M, cn[3][1024] 65M, amin[3][16384] 66M (384KB),
    //              rn 67M, zqb [68,76M), wt1 76M (256KB)
    //   [96,112M)  z f32 (dead after LN -> zq); before G3: W1T/W2T splits
    //   [112,128M) r f32 (written by LN); before LN: W3T splits at 112M/113M
    char* ws = (char*)d_ws;
    unsigned short* h1h = (unsigned short*)(ws);
    unsigned short* h1l = (unsigned short*)(ws + (32u << 20));
    unsigned short* h2h = (unsigned short*)(ws + (64u << 20));
    unsigned short* h2l = (unsigned short*)(ws + (80u << 20));
    float* z     = (float*)(ws + (96u << 20));
    float* r     = (float*)(ws + (112u << 20));
    float* zq    = (float*)(ws + (96u << 20));
    unsigned short* w1th = (unsigned short*)(ws + (96u << 20));    // 4MB
    unsigned short* w1tl = (unsigned short*)(ws + (100u << 20));   // 4MB
    unsigned short* w2th = (unsigned short*)(ws + (104u << 20));   // 1MB
    unsigned short* w2tl = (unsigned short*)(ws + (105u << 20));   // 1MB
    unsigned short* w3th = (unsigned short*)(ws + (112u << 20));   // 256KB (in r, dead before LN)
    unsigned short* w3tl = (unsigned short*)(ws + (113u << 20));   // 256KB
    unsigned short* d1  = (unsigned short*)(ws);
    unsigned short* d2  = (unsigned short*)(ws + (16u << 20));
    unsigned short* wt3 = (unsigned short*)(ws + (48u << 20));
    unsigned short* wt2 = (unsigned short*)(ws + (52u << 20));
    float* lossf = (float*)(ws + (64u << 20));
    float* cn3   = (float*)(ws + (65u << 20));
    unsigned long long* amin3 = (unsigned long long*)(ws + (66u << 20));
    float* rnb   = (float*)(ws + (67u << 20));
    unsigned short* zqb = (unsigned short*)(ws + (68u << 20));     // 8MB
    unsigned short* wt1 = (unsigned short*)(ws + (76u << 20));     // 256KB

    float* xhat     = (float*)d_out;
    float* loss_out = xhat + (size_t)B * D_IN;
    float* idx_out  = loss_out + B;

    // encoder weight split+transpose (f16 hi/lo, x32 scaled)
    wsplit_t<<<dim3(H1 / 32, D_IN / 32), 256, 0, stream>>>(enc_W1, w1th, w1tl, D_IN, H1);
    wsplit_t<<<dim3(H2 / 32, H1 / 32), 256, 0, stream>>>(enc_W2, w2th, w2tl, H1, H2);
    wsplit_t<<<dim3(D_LAT / 32, H2 / 32), 256, 0, stream>>>(enc_W3, w3th, w3tl, H2, D_LAT);

    // encoder: f32-accuracy split-f16 MFMA GEMMs (pipelined)
    gemm_f16x2<true, true, true><<<dim3(H1 / 128, B / 128), 256, 0, stream>>>(
        x, nullptr, nullptr, w1th, w1tl, enc_b1, h1h, h1l, B, H1, D_IN);
    gemm_f16x2<false, true, true><<<dim3(H2 / 128, B / 128), 256, 0, stream>>>(
        nullptr, h1h, h1l, w2th, w2tl, enc_b2, h2h, h2l, B, H2, H1);
    // decoder weight prep (h1 region partially dead now; wt2/wt3 live in h1l)
    wtrans<<<dim3(H1 / 32, H2 / 32), 256, 0, stream>>>(dec_W2, wt2, H2, H1);
    wtrans<<<dim3(D_IN / 32, H1 / 32), 256, 0, stream>>>(dec_W3, wt3, H1, D_IN);
    gemm_f16x2<false, false, false><<<dim3(D_LAT / 128, B / 128), 256, 0, stream>>>(
        nullptr, h2h, h2l, w3th, w3tl, enc_b3, z, nullptr, B, D_LAT, H2);
    ln_kernel<<<B / 4, 256, 0, stream>>>(z, ln_g, ln_b, r);

    // h2 region dead after G3: cn/amin for all 3 stages + dec_W1 transpose
    cninit3<<<192, 256, 0, stream>>>(cb0, cb1, cb2, cn3, amin3);
    wtrans<<<dim3(H2 / 32, D_LAT / 32), 256, 0, stream>>>(dec_W1, wt1, D_LAT, H2);

    // residual VQ (f32 argmin-exact path, round-3 vq_dist)
    const float* cbs[3] = {cb0, cb1, cb2};
    for (int s = 0; s < 3; ++s) {
        rn_kernel<<<B / 16, 256, 0, stream>>>(r, rnb);
        vq_dist<<<dim3(1024 / 128, B / 128), 256, 0, stream>>>(
            r, cbs[s], rnb, cn3 + s * 1024, amin3 + (size_t)s * 16384);
        vq_update<<<B / 16, 256, 0, stream>>>(
            r, zq, lossf, cbs[s], amin3 + (size_t)s * 16384, idx_out, zqb, s);
    }

    // decoder (all 128x128 pipelined bf16 MFMA)
    gemm_bt128<true, false><<<dim3(H2 / 128, B / 128), 256, 0, stream>>>(
        zqb, wt1, dec_b1, d1, B, H2, D_LAT);
    gemm_bt128<true, false><<<dim3(H1 / 128, B / 128), 256, 0, stream>>>(
        d1, wt2, dec_b2, d2, B, H1, H2);
    gemm_bt128<false, true><<<dim3(D_IN / 128, B / 128), 256, 0, stream>>>(
        d2, wt3, dec_b3, xhat, B, D_IN, H1);
    recon_kernel<<<B, 256, 0, stream>>>(xhat, x, lossf, loss_out);
}